// Round 5
// baseline (289.639 us; speedup 1.0000x reference)
//
#include <hip/hip_runtime.h>
#include <hip/hip_bf16.h>

#define NCLS   100000
#define NPAD   100096   // 782 * 128
#define BATCH  1024
#define EDIM   512

#define COS_M_  0.8775825618903728f
#define SIN_M_  0.479425538604203f
#define TH_     (-0.8775825618903728f)
#define MM_     0.2397127693021015f
#define SCALE_  64.0f

typedef __attribute__((ext_vector_type(8))) short short8;
typedef __attribute__((ext_vector_type(4))) float f32x4;

__device__ __forceinline__ ushort f2bf(float f) {
    // round-to-nearest-even f32 -> bf16 (inputs are finite, no NaN handling needed)
    uint u = __float_as_uint(f);
    u += 0x7fffu + ((u >> 16) & 1u);
    return (ushort)(u >> 16);
}

// One 64-lane wave per row: L2-normalize 512 f32 -> 512 bf16.
// Rows in [rows, padrows) are zero-filled (N-padding for the GEMM).
__global__ __launch_bounds__(256) void norm_rows_kernel(
    const float* __restrict__ in, ushort* __restrict__ out,
    int rows, int padrows)
{
    int gw   = (int)((blockIdx.x * blockDim.x + threadIdx.x) >> 6);
    int lane = (int)(threadIdx.x & 63);
    if (gw >= padrows) return;
    ushort* op = out + (size_t)gw * EDIM + lane * 8;
    if (gw >= rows) {
        uint4 z = make_uint4(0u, 0u, 0u, 0u);
        *(uint4*)op = z;
        return;
    }
    const float* ip = in + (size_t)gw * EDIM + lane * 8;
    float4 x0 = *(const float4*)ip;
    float4 x1 = *(const float4*)(ip + 4);
    float ss = x0.x*x0.x + x0.y*x0.y + x0.z*x0.z + x0.w*x0.w
             + x1.x*x1.x + x1.y*x1.y + x1.z*x1.z + x1.w*x1.w;
    #pragma unroll
    for (int off = 32; off; off >>= 1) ss += __shfl_xor(ss, off, 64);
    float inv = 1.0f / fmaxf(sqrtf(ss), 1e-12f);
    uint w0 = (uint)f2bf(x0.x*inv) | ((uint)f2bf(x0.y*inv) << 16);
    uint w1 = (uint)f2bf(x0.z*inv) | ((uint)f2bf(x0.w*inv) << 16);
    uint w2 = (uint)f2bf(x1.x*inv) | ((uint)f2bf(x1.y*inv) << 16);
    uint w3 = (uint)f2bf(x1.z*inv) | ((uint)f2bf(x1.w*inv) << 16);
    uint4 r; r.x = w0; r.y = w1; r.z = w2; r.w = w3;
    *(uint4*)op = r;
}

// Margin fixup: only the 1024 (row, label[row]) entries need the ArcFace
// margin. GEMM stored clamp(cos)*64; recover cos = v/64 (exact, pow2 scale),
// apply margin, rewrite.
__global__ __launch_bounds__(256) void fixup_labels_kernel(
    const int* __restrict__ labels, float* __restrict__ C)
{
    int row = (int)(blockIdx.x * blockDim.x + threadIdx.x);
    if (row >= BATCH) return;
    int lab = labels[row];
    float* p = C + (size_t)row * NCLS + lab;
    float c = *p * (1.0f / SCALE_);
    float s  = sqrtf(1.0f - c * c);
    float cm = c * COS_M_ - s * SIN_M_;
    cm = (c > TH_) ? cm : (c - MM_);
    *p = cm * SCALE_;
}

#define GLL16(g, s) __builtin_amdgcn_global_load_lds(                    \
    (const __attribute__((address_space(1))) void*)(g),                  \
    (__attribute__((address_space(3))) void*)(s), 16, 0, 0)

// 128x128 tile, BK=32, 4 waves (2x2), mfma_f32_16x16x32_bf16 with SWAPPED
// operands (mfma(b,a)) so each lane's 4 acc regs are 4 consecutive N-columns
// -> dwordx4 C stores. Depth-3 circular LDS pipeline, counted vmcnt + raw
// s_barrier, XOR-swizzled K-slots, T1 XCD chunk swizzle. Epilogue is just
// clamp+scale+store (margin handled by fixup_labels_kernel).
__global__ __launch_bounds__(256, 3) void gemm_arc_kernel(
    const ushort* __restrict__ A,
    const ushort* __restrict__ B,
    float* __restrict__ C)
{
    // 3 buffers x (A:8KB + B:8KB) = 48 KB -> 3 blocks/CU
    __shared__ __align__(16) ushort Als[3][128 * 32];
    __shared__ __align__(16) ushort Bls[3][128 * 32];

    const int t    = (int)threadIdx.x;
    const int lane = t & 63;
    const int w    = t >> 6;
    const int wrow = w >> 1, wcol = w & 1;
    const int lr   = lane & 15, lg = lane >> 4;

    // T1 bijective XCD swizzle: the 8 M-blocks sharing a B-tile land on ONE XCD.
    const int nwg  = (int)gridDim.x;         // 6256, %8 == 0
    const int cpx  = nwg >> 3;               // 782
    const int bid  = (int)blockIdx.x;
    const int swz  = (bid & 7) * cpx + (bid >> 3);
    const int brow = swz & 7;                // M-tile (0..7)
    const int bcol = swz >> 3;               // N-tile (0..781)

    const f32x4 z4 = {0.f, 0.f, 0.f, 0.f};
    f32x4 acc[4][4];
    #pragma unroll
    for (int i = 0; i < 4; ++i)
        #pragma unroll
        for (int j = 0; j < 4; ++j) acc[i][j] = z4;

    // staging: 256 threads x 16 B = 4 KB per instruction = 64 rows x 64 B.
    // LDS dest linear; global SOURCE byte offset carries the inverse K-slot
    // swizzle off' ^= ((row>>1)&3)<<4.
    const int srow = t >> 2;
    const int scb  = ((t & 3) * 16) ^ (((t >> 3) & 3) << 4);
    const char* Ab = (const char*)(A + ((size_t)brow * 128 + srow) * EDIM) + scb;
    const char* Bb = (const char*)(B + ((size_t)bcol * 128 + srow) * EDIM) + scb;
    const uint ldsw = (uint)w * 1024;        // wave-uniform LDS base (+lane*16 in HW)

    // ds_read side: row R, byte (lg*16) ^ ((R>>1)&3)<<4; for R = base16+lr the
    // XOR term is the per-lane constant ((lr>>1)&3)<<4.
    const int kswz  = ((lr >> 1) & 3) << 4;
    const int aoff0 = (wrow * 64 + lr) * 64 + ((lg * 16) ^ kswz);
    const int boff0 = (wcol * 64 + lr) * 64 + ((lg * 16) ^ kswz);

#define STAGE(c, kt) do {                                                  \
        const char* a0 = Ab + (kt) * 64;                                   \
        const char* b0 = Bb + (kt) * 64;                                   \
        char* Ad = (char*)Als + (size_t)(c) * 8192 + ldsw;                 \
        char* Bd = (char*)Bls + (size_t)(c) * 8192 + ldsw;                 \
        GLL16(a0,                 Ad);                                     \
        GLL16(a0 + 64 * EDIM * 2, Ad + 4096);                              \
        GLL16(b0,                 Bd);                                     \
        GLL16(b0 + 64 * EDIM * 2, Bd + 4096);                              \
    } while (0)

// Swapped operands: mfma(bv, av) -> acc[mi][ni][reg] =
//   C[mbase + mi*16 + lr][nbase + ni*16 + lg*4 + reg]
#define COMPUTE(c) do {                                                    \
        const char* Ap = (const char*)Als + (size_t)(c) * 8192;            \
        const char* Bp = (const char*)Bls + (size_t)(c) * 8192;            \
        short8 av[4], bv[4];                                               \
        _Pragma("unroll")                                                  \
        for (int mi = 0; mi < 4; ++mi)                                     \
            av[mi] = *(const short8*)(Ap + aoff0 + mi * 1024);             \
        _Pragma("unroll")                                                  \
        for (int ni = 0; ni < 4; ++ni)                                     \
            bv[ni] = *(const short8*)(Bp + boff0 + ni * 1024);             \
        __builtin_amdgcn_s_setprio(1);                                     \
        _Pragma("unroll")                                                  \
        for (int mi = 0; mi < 4; ++mi)                                     \
            _Pragma("unroll")                                              \
            for (int ni = 0; ni < 4; ++ni)                                 \
                acc[mi][ni] = __builtin_amdgcn_mfma_f32_16x16x32_bf16(     \
                    bv[ni], av[mi], acc[mi][ni], 0, 0, 0);                 \
        __builtin_amdgcn_s_setprio(0);                                     \
    } while (0)

    // prologue: stage tiles 0,1 (8 loads in flight)
    STAGE(0, 0);
    STAGE(1, 1);

    // main loop: stage kt+2, wait ONLY for tile kt (vmcnt(8) leaves tiles
    // kt+1,kt+2 in flight across the barrier), compute kt. Every wave waits
    // its own tile-kt loads before the barrier, so after the barrier the
    // whole tile is in LDS.
    #pragma unroll
    for (int kt = 0; kt < 14; ++kt) {
        asm volatile("s_waitcnt lgkmcnt(0)" ::: "memory");
        __builtin_amdgcn_s_barrier();
        STAGE((kt + 2) % 3, kt + 2);
        asm volatile("s_waitcnt vmcnt(8)" ::: "memory");
        __builtin_amdgcn_s_barrier();
        COMPUTE(kt % 3);
    }
    // tail: tiles 14,15 already staged; drain 4 then 0
    asm volatile("s_waitcnt vmcnt(4)" ::: "memory");
    __builtin_amdgcn_s_barrier();
    COMPUTE(14 % 3);
    asm volatile("s_waitcnt vmcnt(0)" ::: "memory");
    __builtin_amdgcn_s_barrier();
    COMPUTE(15 % 3);

    // Epilogue: clamp + scale + dwordx4 store. Fragment (mi,ni): lane lr is
    // M-row mbase+mi*16+lr, regs are N-cols nbase+ni*16+lg*4 .. +3.
    // 100000 % 16 == 0, so the N-edge guard is fragment-granular.
    const int mbase = brow * 128 + wrow * 64;
    const int nbase = bcol * 128 + wcol * 64;
    #pragma unroll
    for (int mi = 0; mi < 4; ++mi) {
        const int grow = mbase + mi * 16 + lr;
        float* crow = C + (size_t)grow * NCLS;
        #pragma unroll
        for (int ni = 0; ni < 4; ++ni) {
            if (nbase + ni * 16 < NCLS) {
                f32x4 v = acc[mi][ni];
                f32x4 o;
                #pragma unroll
                for (int j = 0; j < 4; ++j) {
                    float c = fminf(fmaxf(v[j], -1.0f + 1e-7f), 1.0f - 1e-7f);
                    o[j] = c * SCALE_;
                }
                *(f32x4*)&crow[nbase + ni * 16 + lg * 4] = o;
            }
        }
    }
#undef STAGE
#undef COMPUTE
}

extern "C" void kernel_launch(void* const* d_in, const int* in_sizes, int n_in,
                              void* d_out, int out_size, void* d_ws, size_t ws_size,
                              hipStream_t stream)
{
    const float* emb    = (const float*)d_in[0];
    const int*   labels = (const int*)d_in[1];
    const float* wgt    = (const float*)d_in[2];
    float*       out    = (float*)d_out;

    // workspace layout: [Ebf: 1024*512 bf16 = 1 MB][Wbf: 100096*512 bf16 = 102.5 MB]
    ushort* Ebf = (ushort*)d_ws;
    ushort* Wbf = (ushort*)((char*)d_ws + (size_t)BATCH * EDIM * 2);

    norm_rows_kernel<<<BATCH / 4, 256, 0, stream>>>(emb, Ebf, BATCH, BATCH);
    norm_rows_kernel<<<NPAD / 4, 256, 0, stream>>>(wgt, Wbf, NCLS, NPAD);

    gemm_arc_kernel<<<BATCH / 128 * (NPAD / 128), 256, 0, stream>>>(Ebf, Wbf, out);

    fixup_labels_kernel<<<BATCH / 256, 256, 0, stream>>>(labels, out);
}

// Round 6
// 283.606 us; speedup vs baseline: 1.0213x; 1.0213x over previous
//
#include <hip/hip_runtime.h>
#include <hip/hip_bf16.h>

#define NCLS   100000
#define NPAD   100096   // 391 * 256
#define BATCH  1024
#define EDIM   512

#define COS_M_  0.8775825618903728f
#define SIN_M_  0.479425538604203f
#define TH_     (-0.8775825618903728f)
#define MM_     0.2397127693021015f
#define SCALE_  64.0f

typedef __attribute__((ext_vector_type(8))) short short8;
typedef __attribute__((ext_vector_type(4))) float f32x4;

__device__ __forceinline__ ushort f2bf(float f) {
    // round-to-nearest-even f32 -> bf16 (inputs are finite, no NaN handling needed)
    uint u = __float_as_uint(f);
    u += 0x7fffu + ((u >> 16) & 1u);
    return (ushort)(u >> 16);
}

// One 64-lane wave per row: L2-normalize 512 f32 -> 512 bf16.
// Rows in [rows, padrows) are zero-filled (N-padding for the GEMM).
__global__ __launch_bounds__(256) void norm_rows_kernel(
    const float* __restrict__ in, ushort* __restrict__ out,
    int rows, int padrows)
{
    int gw   = (int)((blockIdx.x * blockDim.x + threadIdx.x) >> 6);
    int lane = (int)(threadIdx.x & 63);
    if (gw >= padrows) return;
    ushort* op = out + (size_t)gw * EDIM + lane * 8;
    if (gw >= rows) {
        uint4 z = make_uint4(0u, 0u, 0u, 0u);
        *(uint4*)op = z;
        return;
    }
    const float* ip = in + (size_t)gw * EDIM + lane * 8;
    float4 x0 = *(const float4*)ip;
    float4 x1 = *(const float4*)(ip + 4);
    float ss = x0.x*x0.x + x0.y*x0.y + x0.z*x0.z + x0.w*x0.w
             + x1.x*x1.x + x1.y*x1.y + x1.z*x1.z + x1.w*x1.w;
    #pragma unroll
    for (int off = 32; off; off >>= 1) ss += __shfl_xor(ss, off, 64);
    float inv = 1.0f / fmaxf(sqrtf(ss), 1e-12f);
    uint w0 = (uint)f2bf(x0.x*inv) | ((uint)f2bf(x0.y*inv) << 16);
    uint w1 = (uint)f2bf(x0.z*inv) | ((uint)f2bf(x0.w*inv) << 16);
    uint w2 = (uint)f2bf(x1.x*inv) | ((uint)f2bf(x1.y*inv) << 16);
    uint w3 = (uint)f2bf(x1.z*inv) | ((uint)f2bf(x1.w*inv) << 16);
    uint4 r; r.x = w0; r.y = w1; r.z = w2; r.w = w3;
    *(uint4*)op = r;
}

// Margin fixup: only the 1024 (row, label[row]) entries need the ArcFace
// margin. GEMM stored clamp(cos)*64; recover cos = v/64 (exact, pow2 scale),
// apply margin, rewrite.
__global__ __launch_bounds__(256) void fixup_labels_kernel(
    const int* __restrict__ labels, float* __restrict__ C)
{
    int row = (int)(blockIdx.x * blockDim.x + threadIdx.x);
    if (row >= BATCH) return;
    int lab = labels[row];
    float* p = C + (size_t)row * NCLS + lab;
    float c = *p * (1.0f / SCALE_);
    float s  = sqrtf(1.0f - c * c);
    float cm = c * COS_M_ - s * SIN_M_;
    cm = (c > TH_) ? cm : (c - MM_);
    *p = cm * SCALE_;
}

#define GLL16(g, s) __builtin_amdgcn_global_load_lds(                    \
    (const __attribute__((address_space(1))) void*)(g),                  \
    (__attribute__((address_space(3))) void*)(s), 16, 0, 0)

// 128x256 block tile, BK=32, 4 waves (2x2), wave tile 64 M x 128 N:
// acc[4][8] fragments -> 32 MFMA per wave per K-step against 12 KB LDS reads
// (2x the FLOP/LDS-byte of the 64x64 wave tile; LDS pipe was the ceiling).
// Depth-3 circular LDS pipeline with counted vmcnt + raw s_barrier.
// XOR-swizzled K-slots (pre-swizzled global source + swizzled ds_read; LDS
// dest linear for global_load_lds), T1 XCD chunk swizzle. Swapped-operand
// MFMA -> each lane's 4 acc regs are 4 consecutive N-cols -> dwordx4 stores.
// Epilogue: clamp+scale only (margin via fixup_labels_kernel).
__global__ __launch_bounds__(256, 2) void gemm_arc_kernel(
    const ushort* __restrict__ A,
    const ushort* __restrict__ B,
    float* __restrict__ C)
{
    // 3 buffers: A 8 KB + B 16 KB each -> 72 KB -> 2 blocks/CU
    __shared__ __align__(16) ushort Als[3][128 * 32];
    __shared__ __align__(16) ushort Bls[3][256 * 32];

    const int t    = (int)threadIdx.x;
    const int lane = t & 63;
    const int w    = t >> 6;
    const int wrow = w >> 1, wcol = w & 1;    // 2x2 waves; wave tile 64M x 128N
    const int lr   = lane & 15, lg = lane >> 4;

    // T1 bijective XCD swizzle: the 8 M-blocks sharing a B-panel land on ONE
    // XCD. nwg = 3128, %8 == 0.
    const int nwg  = (int)gridDim.x;
    const int cpx  = nwg >> 3;                // 391
    const int bid  = (int)blockIdx.x;
    const int swz  = (bid & 7) * cpx + (bid >> 3);
    const int brow = swz & 7;                 // M-tile (0..7)
    const int bcol = swz >> 3;                // N-tile (0..390)

    const f32x4 z4 = {0.f, 0.f, 0.f, 0.f};
    f32x4 acc[4][8];
    #pragma unroll
    for (int i = 0; i < 4; ++i)
        #pragma unroll
        for (int j = 0; j < 8; ++j) acc[i][j] = z4;

    // staging: 256 threads x 16 B = 4 KB per instruction = 64 rows x 64 B.
    // A tile: 128 rows -> 2 insts; B tile: 256 rows -> 4 insts.
    // LDS dest linear; global SOURCE byte offset carries the inverse K-slot
    // swizzle off' ^= ((row>>1)&3)<<4 (row offsets 64/128/192 are == 0 mod 4
    // after >>1, so one swizzled base serves all chunks).
    const int srow = t >> 2;
    const int scb  = ((t & 3) * 16) ^ (((t >> 3) & 3) << 4);
    const char* Ab = (const char*)(A + ((size_t)brow * 128 + srow) * EDIM) + scb;
    const char* Bb = (const char*)(B + ((size_t)bcol * 256 + srow) * EDIM) + scb;
    const uint ldsw = (uint)w * 1024;         // wave-uniform LDS base (+lane*16 HW)

    // ds_read side: row R, byte (lg*16) ^ ((R>>1)&3)<<4. All our R patterns
    // are (16-mult + lr), so the XOR term is the per-lane const ((lr>>1)&3)<<4.
    const int kswz  = ((lr >> 1) & 3) << 4;
    const int aoff0 = (wrow * 64  + lr) * 64 + ((lg * 16) ^ kswz);
    const int boff0 = (wcol * 128 + lr) * 64 + ((lg * 16) ^ kswz);

#define STAGE(c, kt) do {                                                  \
        const char* a0 = Ab + (kt) * 64;                                   \
        const char* b0 = Bb + (kt) * 64;                                   \
        char* Ad = (char*)Als + (size_t)(c) * 8192  + ldsw;                \
        char* Bd = (char*)Bls + (size_t)(c) * 16384 + ldsw;                \
        GLL16(a0,                  Ad);                                    \
        GLL16(a0 +  64 * EDIM * 2, Ad + 4096);                             \
        GLL16(b0,                  Bd);                                    \
        GLL16(b0 +  64 * EDIM * 2, Bd + 4096);                             \
        GLL16(b0 + 128 * EDIM * 2, Bd + 8192);                             \
        GLL16(b0 + 192 * EDIM * 2, Bd + 12288);                            \
    } while (0)

// Swapped operands: mfma(bv, av) -> acc[mi][ni][reg] =
//   C[mbase + mi*16 + lr][nbase + ni*16 + lg*4 + reg]
#define COMPUTE(c) do {                                                    \
        const char* Ap = (const char*)Als + (size_t)(c) * 8192;            \
        const char* Bp = (const char*)Bls + (size_t)(c) * 16384;           \
        short8 av[4], bv[8];                                               \
        _Pragma("unroll")                                                  \
        for (int mi = 0; mi < 4; ++mi)                                     \
            av[mi] = *(const short8*)(Ap + aoff0 + mi * 1024);             \
        _Pragma("unroll")                                                  \
        for (int ni = 0; ni < 8; ++ni)                                     \
            bv[ni] = *(const short8*)(Bp + boff0 + ni * 1024);             \
        _Pragma("unroll")                                                  \
        for (int mi = 0; mi < 4; ++mi)                                     \
            _Pragma("unroll")                                              \
            for (int ni = 0; ni < 8; ++ni)                                 \
                acc[mi][ni] = __builtin_amdgcn_mfma_f32_16x16x32_bf16(     \
                    bv[ni], av[mi], acc[mi][ni], 0, 0, 0);                 \
    } while (0)

    // prologue: stage tiles 0,1 (12 loads in flight)
    STAGE(0, 0);
    STAGE(1, 1);

    // main loop: stage kt+2, wait ONLY for tile kt (vmcnt(12) leaves tiles
    // kt+1,kt+2 in flight across the barrier), compute kt.
    #pragma unroll
    for (int kt = 0; kt < 14; ++kt) {
        // protect buffer (kt+2)%3 (= (kt-1)%3) from overwrite until all waves
        // finished their ds_reads of it in COMPUTE(kt-1)
        asm volatile("s_waitcnt lgkmcnt(0)" ::: "memory");
        __builtin_amdgcn_s_barrier();
        STAGE((kt + 2) % 3, kt + 2);
        asm volatile("s_waitcnt vmcnt(12)" ::: "memory");
        __builtin_amdgcn_s_barrier();
        COMPUTE(kt % 3);
    }
    // tail: tiles 14,15 already staged; drain 6 then 0
    asm volatile("s_waitcnt vmcnt(6)" ::: "memory");
    __builtin_amdgcn_s_barrier();
    COMPUTE(14 % 3);
    asm volatile("s_waitcnt vmcnt(0)" ::: "memory");
    __builtin_amdgcn_s_barrier();
    COMPUTE(15 % 3);

    // Epilogue: clamp + scale + dwordx4 stores. Fragment (mi,ni): lane lr is
    // M-row mbase+mi*16+lr, regs are N-cols nbase+ni*16+lg*4 .. +3.
    // NCLS % 16 == 0, so the N-edge guard is fragment-granular.
    const int mbase = brow * 128 + wrow * 64;
    const int nbase = bcol * 256 + wcol * 128;
    #pragma unroll
    for (int mi = 0; mi < 4; ++mi) {
        const int grow = mbase + mi * 16 + lr;
        float* crow = C + (size_t)grow * NCLS;
        #pragma unroll
        for (int ni = 0; ni < 8; ++ni) {
            if (nbase + ni * 16 < NCLS) {
                f32x4 v = acc[mi][ni];
                f32x4 o;
                #pragma unroll
                for (int j = 0; j < 4; ++j) {
                    float c = fminf(fmaxf(v[j], -1.0f + 1e-7f), 1.0f - 1e-7f);
                    o[j] = c * SCALE_;
                }
                *(f32x4*)&crow[nbase + ni * 16 + lg * 4] = o;
            }
        }
    }
#undef STAGE
#undef COMPUTE
}

extern "C" void kernel_launch(void* const* d_in, const int* in_sizes, int n_in,
                              void* d_out, int out_size, void* d_ws, size_t ws_size,
                              hipStream_t stream)
{
    const float* emb    = (const float*)d_in[0];
    const int*   labels = (const int*)d_in[1];
    const float* wgt    = (const float*)d_in[2];
    float*       out    = (float*)d_out;

    // workspace layout: [Ebf: 1024*512 bf16 = 1 MB][Wbf: 100096*512 bf16 = 102.5 MB]
    ushort* Ebf = (ushort*)d_ws;
    ushort* Wbf = (ushort*)((char*)d_ws + (size_t)BATCH * EDIM * 2);

    norm_rows_kernel<<<BATCH / 4, 256, 0, stream>>>(emb, Ebf, BATCH, BATCH);
    norm_rows_kernel<<<NPAD / 4, 256, 0, stream>>>(wgt, Wbf, NCLS, NPAD);

    gemm_arc_kernel<<<(BATCH / 128) * (NPAD / 256), 256, 0, stream>>>(Ebf, Wbf, out);

    fixup_labels_kernel<<<BATCH / 256, 256, 0, stream>>>(labels, out);
}

// Round 7
// 273.984 us; speedup vs baseline: 1.0571x; 1.0351x over previous
//
#include <hip/hip_runtime.h>
#include <hip/hip_bf16.h>

#define NCLS   100000
#define NPAD   100096   // 391 * 256
#define BATCH  1024
#define EDIM   512

#define COS_M_  0.8775825618903728f
#define SIN_M_  0.479425538604203f
#define TH_     (-0.8775825618903728f)
#define MM_     0.2397127693021015f
#define SCALE_  64.0f

typedef __attribute__((ext_vector_type(8))) short short8;
typedef __attribute__((ext_vector_type(4))) float f32x4;

__device__ __forceinline__ ushort f2bf(float f) {
    uint u = __float_as_uint(f);
    u += 0x7fffu + ((u >> 16) & 1u);
    return (ushort)(u >> 16);
}

// One 64-lane wave per row: L2-normalize 512 f32 -> 512 bf16.
__global__ __launch_bounds__(256) void norm_rows_kernel(
    const float* __restrict__ in, ushort* __restrict__ out,
    int rows, int padrows)
{
    int gw   = (int)((blockIdx.x * blockDim.x + threadIdx.x) >> 6);
    int lane = (int)(threadIdx.x & 63);
    if (gw >= padrows) return;
    ushort* op = out + (size_t)gw * EDIM + lane * 8;
    if (gw >= rows) {
        uint4 z = make_uint4(0u, 0u, 0u, 0u);
        *(uint4*)op = z;
        return;
    }
    const float* ip = in + (size_t)gw * EDIM + lane * 8;
    float4 x0 = *(const float4*)ip;
    float4 x1 = *(const float4*)(ip + 4);
    float ss = x0.x*x0.x + x0.y*x0.y + x0.z*x0.z + x0.w*x0.w
             + x1.x*x1.x + x1.y*x1.y + x1.z*x1.z + x1.w*x1.w;
    #pragma unroll
    for (int off = 32; off; off >>= 1) ss += __shfl_xor(ss, off, 64);
    float inv = 1.0f / fmaxf(sqrtf(ss), 1e-12f);
    uint w0 = (uint)f2bf(x0.x*inv) | ((uint)f2bf(x0.y*inv) << 16);
    uint w1 = (uint)f2bf(x0.z*inv) | ((uint)f2bf(x0.w*inv) << 16);
    uint w2 = (uint)f2bf(x1.x*inv) | ((uint)f2bf(x1.y*inv) << 16);
    uint w3 = (uint)f2bf(x1.z*inv) | ((uint)f2bf(x1.w*inv) << 16);
    uint4 r; r.x = w0; r.y = w1; r.z = w2; r.w = w3;
    *(uint4*)op = r;
}

// Margin fixup on the 1024 (row, label) entries only.
__global__ __launch_bounds__(256) void fixup_labels_kernel(
    const int* __restrict__ labels, float* __restrict__ C)
{
    int row = (int)(blockIdx.x * blockDim.x + threadIdx.x);
    if (row >= BATCH) return;
    int lab = labels[row];
    float* p = C + (size_t)row * NCLS + lab;
    float c = *p * (1.0f / SCALE_);
    float s  = sqrtf(1.0f - c * c);
    float cm = c * COS_M_ - s * SIN_M_;
    cm = (c > TH_) ? cm : (c - MM_);
    *p = cm * SCALE_;
}

#define GLL16(g, s) __builtin_amdgcn_global_load_lds(                    \
    (const __attribute__((address_space(1))) void*)(g),                  \
    (__attribute__((address_space(3))) void*)(s), 16, 0, 0)

// ===== 8-phase 256x256 GEMM (T1+T2+T3+T4+T5), BK=64, 8 waves (2M x 4N) =====
// Wave tile 128M x 64N, acc[8][4] f32x4. LDS: 2 dbuf x (A 32KB + B 32KB) =
// 128 KB, 1 block/CU. Per K-tile: 4 phases x {ds_read subtile | stage 1
// half-tile | bar | lgkm(0) | setprio+16 MFMA | bar}; ONE counted vmcnt(4)
// per K-tile (2 half-tiles always in flight). LDS swizzle: 16B-slot ^= row&7
// (inverse pre-applied on the global gll source; per-lane constants on
// ds_read). Swapped-operand MFMA -> lane's 4 acc regs = 4 consecutive N cols.
// Stage legality (derived): A-half h of tile S+1 staged at S.P0/P1 overwrites
// A-half(S-1), retired at (S-1).P3's trailing barrier; B halves of S+2 staged
// at S.P3 overwrite B(S), retired at S.P2's trailing barrier.
__global__ __launch_bounds__(512, 2) void gemm_arc_kernel(
    const ushort* __restrict__ A,
    const ushort* __restrict__ B,
    float* __restrict__ C)
{
    __shared__ __align__(16) ushort Als[2][256 * 64];  // 64 KB
    __shared__ __align__(16) ushort Bls[2][256 * 64];  // 64 KB

    const int t    = (int)threadIdx.x;          // 0..511
    const int lane = t & 63;
    const int w    = t >> 6;                    // 0..7
    const int wr   = w >> 2, wc = w & 3;        // 2M x 4N waves
    const int lr   = lane & 15, lg = lane >> 4;

    // Bijective XCD chunk swizzle (nwg=1564: q=195, r=4), M fastest so the
    // 4 M-blocks sharing a B-panel are contiguous logical ids on one XCD.
    const int nwg = (int)gridDim.x;
    const int q   = nwg >> 3, r = nwg & 7;
    const int bid = (int)blockIdx.x;
    const int xcd = bid & 7, loc = bid >> 3;
    const int wg  = (xcd < r ? xcd * (q + 1) : r * (q + 1) + (xcd - r) * q) + loc;
    const int brow = wg & 3;                    // M-tile 0..3
    const int bcol = wg >> 2;                   // N-tile 0..390

    const f32x4 z4 = {0.f, 0.f, 0.f, 0.f};
    f32x4 acc[8][4];
    #pragma unroll
    for (int i = 0; i < 8; ++i)
        #pragma unroll
        for (int j = 0; j < 4; ++j) acc[i][j] = z4;

    // Staging: half-tile = 128 rows x 128 B = 2 gll x (512 thr x 16B).
    // Thread t covers row t>>3 (of a 64-row chunk), 16B-slot t&7.
    // Global source carries the inverse swizzle: slot ^= row&7.
    const int srow = t >> 3;
    const int sby  = ((t & 7) * 16) ^ ((srow & 7) << 4);
    const char* Ab = (const char*)(A + ((size_t)brow * 256 + srow) * EDIM) + sby;
    const char* Bb = (const char*)(B + ((size_t)bcol * 256 + srow) * EDIM) + sby;
    const uint ldsw = (uint)w * 1024;           // linear LDS dest (+lane*16 HW)

    // ds_read: row R = (frag*16 + lr [+wave base]), want 16B-slot (ks*4+lg),
    // swizzled slot = (ks*4+lg) ^ (R&7) = (ks*4+lg) ^ (lr&7). Split:
    // low bits (lg ^ (lr&3)) and ks-bit (ks ^ ((lr>>2)&1)).
    const int slo  = (lg ^ (lr & 3)) << 4;
    const int kx   = (lr >> 2) & 1;
    const int kof0 = kx << 6;                   // ks=0 byte offset
    const int kof1 = (kx ^ 1) << 6;             // ks=1 byte offset
    const int abase = (wr * 128 + lr) * 128 + slo;
    const int bbase = (wc * 64  + lr) * 128 + slo;

#define STAGE_A(c, h, kt) do {                                             \
        const char* s_ = Ab + (size_t)(h) * (128 * 1024) + (kt) * 128;     \
        char* d_ = (char*)Als + (size_t)(c) * 32768 + (h) * 16384 + ldsw;  \
        GLL16(s_,             d_);                                         \
        GLL16(s_ + 64 * 1024, d_ + 8192);                                  \
    } while (0)
#define STAGE_B(c, h, kt) do {                                             \
        const char* s_ = Bb + (size_t)(h) * (128 * 1024) + (kt) * 128;     \
        char* d_ = (char*)Bls + (size_t)(c) * 32768 + (h) * 16384 + ldsw;  \
        GLL16(s_,             d_);                                         \
        GLL16(s_ + 64 * 1024, d_ + 8192);                                  \
    } while (0)

#define RD_A(dst, c, mf, kof) \
    dst = *(const short8*)((const char*)Als + (size_t)(c) * 32768 + abase + (mf) * 2048 + (kof))
#define RD_B(dst, c, nf, kof) \
    dst = *(const short8*)((const char*)Bls + (size_t)(c) * 32768 + bbase + (nf) * 2048 + (kof))

#define BAR()    __builtin_amdgcn_s_barrier()
#define LGKM0()  asm volatile("s_waitcnt lgkmcnt(0)" ::: "memory")
#define SCHED0() __builtin_amdgcn_sched_barrier(0)
#define MFMA_Q(mofs, bv) do {                                              \
        __builtin_amdgcn_s_setprio(1);                                     \
        _Pragma("unroll")                                                  \
        for (int mi = 0; mi < 4; ++mi)                                     \
            _Pragma("unroll")                                              \
            for (int ni = 0; ni < 4; ++ni)                                 \
                acc[(mofs) + mi][ni] = __builtin_amdgcn_mfma_f32_16x16x32_bf16( \
                    bv[ni], av[mi], acc[(mofs) + mi][ni], 0, 0, 0);        \
        __builtin_amdgcn_s_setprio(0);                                     \
    } while (0)

    // prologue: tile0 (both mats) + B of tile1; leave B(1) (4 loads) in flight
    STAGE_B(0, 0, 0); STAGE_B(0, 1, 0);
    STAGE_A(0, 0, 0); STAGE_A(0, 1, 0);
    STAGE_B(1, 0, 1); STAGE_B(1, 1, 1);
    asm volatile("s_waitcnt vmcnt(4)" ::: "memory");
    BAR();

    short8 av[4], bv0[4], bv1[4];
    #pragma unroll
    for (int S = 0; S < 8; ++S) {
        const int c = S & 1;
        // ---- P0: B(ks0) + A(mh0,ks0); stage A0(S+1) ----
        RD_B(bv0[0], c, 0, kof0); RD_B(bv0[1], c, 1, kof0);
        RD_B(bv0[2], c, 2, kof0); RD_B(bv0[3], c, 3, kof0);
        RD_A(av[0], c, 0, kof0); RD_A(av[1], c, 1, kof0);
        RD_A(av[2], c, 2, kof0); RD_A(av[3], c, 3, kof0);
        if (S < 7) STAGE_A(c ^ 1, 0, S + 1);
        BAR(); LGKM0(); SCHED0();
        MFMA_Q(0, bv0);
        BAR();
        // ---- P1: A(mh1,ks0); stage A1(S+1) ----
        RD_A(av[0], c, 4, kof0); RD_A(av[1], c, 5, kof0);
        RD_A(av[2], c, 6, kof0); RD_A(av[3], c, 7, kof0);
        if (S < 7) STAGE_A(c ^ 1, 1, S + 1);
        BAR(); LGKM0(); SCHED0();
        MFMA_Q(4, bv0);
        BAR();
        // ---- P2: B(ks1) + A(mh0,ks1) ----
        RD_B(bv1[0], c, 0, kof1); RD_B(bv1[1], c, 1, kof1);
        RD_B(bv1[2], c, 2, kof1); RD_B(bv1[3], c, 3, kof1);
        RD_A(av[0], c, 0, kof1); RD_A(av[1], c, 1, kof1);
        RD_A(av[2], c, 2, kof1); RD_A(av[3], c, 3, kof1);
        BAR(); LGKM0(); SCHED0();
        MFMA_Q(0, bv1);
        BAR();
        // ---- P3: A(mh1,ks1); stage B(S+2); counted vmcnt; bar ----
        RD_A(av[0], c, 4, kof1); RD_A(av[1], c, 5, kof1);
        RD_A(av[2], c, 6, kof1); RD_A(av[3], c, 7, kof1);
        if (S < 6) { STAGE_B(c, 0, S + 2); STAGE_B(c, 1, S + 2); }
        BAR(); LGKM0(); SCHED0();
        MFMA_Q(4, bv1);
        if (S < 6) {
            asm volatile("s_waitcnt vmcnt(4)" ::: "memory");
        } else if (S == 6) {
            asm volatile("s_waitcnt vmcnt(0)" ::: "memory");
        }
        if (S < 7) BAR();
    }

    // Epilogue: clamp+scale, dwordx4 stores.
    // acc[mf][nf][reg]: row = brow*256 + wr*128 + mf*16 + lr,
    //                   col = bcol*256 + wc*64 + nf*16 + lg*4 + reg.
    const int mbase = brow * 256 + wr * 128;
    const int nb    = bcol * 256 + wc * 64;
    #pragma unroll
    for (int mf = 0; mf < 8; ++mf) {
        const int grow = mbase + mf * 16 + lr;
        float* crow = C + (size_t)grow * NCLS;
        #pragma unroll
        for (int nf = 0; nf < 4; ++nf) {
            if (nb + nf * 16 < NCLS) {
                f32x4 v = acc[mf][nf];
                f32x4 o;
                #pragma unroll
                for (int j = 0; j < 4; ++j) {
                    float cc = fminf(fmaxf(v[j], -1.0f + 1e-7f), 1.0f - 1e-7f);
                    o[j] = cc * SCALE_;
                }
                *(f32x4*)&crow[nb + nf * 16 + lg * 4] = o;
            }
        }
    }
#undef STAGE_A
#undef STAGE_B
#undef RD_A
#undef RD_B
#undef BAR
#undef LGKM0
#undef SCHED0
#undef MFMA_Q
}

extern "C" void kernel_launch(void* const* d_in, const int* in_sizes, int n_in,
                              void* d_out, int out_size, void* d_ws, size_t ws_size,
                              hipStream_t stream)
{
    const float* emb    = (const float*)d_in[0];
    const int*   labels = (const int*)d_in[1];
    const float* wgt    = (const float*)d_in[2];
    float*       out    = (float*)d_out;

    ushort* Ebf = (ushort*)d_ws;
    ushort* Wbf = (ushort*)((char*)d_ws + (size_t)BATCH * EDIM * 2);

    norm_rows_kernel<<<BATCH / 4, 256, 0, stream>>>(emb, Ebf, BATCH, BATCH);
    norm_rows_kernel<<<NPAD / 4, 256, 0, stream>>>(wgt, Wbf, NCLS, NPAD);

    gemm_arc_kernel<<<(BATCH / 256) * (NPAD / 256), 512, 0, stream>>>(Ebf, Wbf, out);

    fixup_labels_kernel<<<BATCH / 256, 256, 0, stream>>>(labels, out);
}